// Round 4
// baseline (1193.076 us; speedup 1.0000x reference)
//
#include <hip/hip_runtime.h>
#include <math.h>

// Problem constants
#define R_  128
#define C_  256
#define E_  768
#define H_  12
#define DK_ 64
#define T_  (R_*C_)       // 32768 tokens
#define RS_ 8             // split-K over rows in attn kernel
#define LP  40            // LDS pitch for ctx_mfma only (legacy padded layout)

typedef __attribute__((ext_vector_type(8))) short          bf16x8;
typedef __attribute__((ext_vector_type(4))) float          f32x4;
typedef __attribute__((ext_vector_type(4))) unsigned short u16x4;
typedef __attribute__((ext_vector_type(8))) unsigned short u16x8;

struct HL { unsigned short h, l; };

// fp32 -> (hi, lo) bf16 split via truncation. hi+lo represents f with ~2^-16
// relative error; lo = f - hi is exact in fp32 (Sterbenz), then truncated.
__device__ __forceinline__ HL split2(float f) {
    HL o;
    unsigned int u = __float_as_uint(f);
    o.h = (unsigned short)(u >> 16);
    float r = f - __uint_as_float(u & 0xFFFF0000u);
    o.l = (unsigned short)(__float_as_uint(r) >> 16);
    return o;
}

// async global->LDS, 16 B per lane. LDS dest is wave-uniform base + lane*16.
__device__ __forceinline__ void gload16(const void* g, void* l) {
    __builtin_amdgcn_global_load_lds(
        (const __attribute__((address_space(1))) unsigned int*)g,
        (__attribute__((address_space(3))) unsigned int*)l,
        16, 0, 0);
}

// ---------------------------------------------------------------------------
// Pre-split: fp32 -> planar (hi, lo) bf16. 8 elems/thread, exact grids only.
// ---------------------------------------------------------------------------
__global__ __launch_bounds__(256) void split_kernel(
    const float* __restrict__ src,
    unsigned short* __restrict__ h, unsigned short* __restrict__ l)
{
    const size_t i = ((size_t)blockIdx.x * 256 + threadIdx.x) * 8;
    float4 f0 = *(const float4*)(src + i);
    float4 f1 = *(const float4*)(src + i + 4);
    float v[8] = { f0.x, f0.y, f0.z, f0.w, f1.x, f1.y, f1.z, f1.w };
    u16x8 hh, ll;
    #pragma unroll
    for (int j = 0; j < 8; ++j) { HL e = split2(v[j]); hh[j] = e.h; ll[j] = e.l; }
    *(u16x8*)(h + i) = hh;
    *(u16x8*)(l + i) = ll;
}

// ---------------------------------------------------------------------------
// GEMM: Y[m,n] = (sum_k A[m,k]*B[n,k] + bias[n]) * scale
// Operands pre-split planar bf16. M x 768 x 768, 128x128 block tile, BK=32,
// 256 threads (2x2 waves of 64x64 wave tiles), mfma_f32_16x16x32_bf16 with
// 3-term hi/lo product.
//
// KEY (R4): the LDS pipe was the bottleneck (reads ~3x the MFMA-pipe time).
// B (the 768x768 weight, L2/L3-hot: reused by every m-block) is now loaded
// DIRECTLY global->VGPR in fragment layout (lane: row n0+wn+u*16+fr, 16 B at
// kq) -- no LDS staging, no LDS reads for B. Only A goes through LDS
// (HBM reuse across 6 n-blocks + per-lane row scatter needs the transpose).
// LDS traffic per K-step halves: 64KB reads + 32KB writes -> 32KB + 16KB.
//
// Loop: R2-proven dbuf + one __syncthreads per K-step. B-frag loads issue
// FIRST (sched_barrier pins them above the A-prefetch) so the compiler's
// wait for B retires only B, leaving the A-prefetch gloads in flight until
// the next barrier -- one full MFMA phase of latency cover.
// A staging: wave w stages rows (w&1)*64..+63 of plane (w>>1) via 4x
// gload16. Granule swizzle: granule g of row r at slot g ^ ((r>>1)&3)
// (pre-swizzled global source, linear LDS dest); reads XOR the same term
// -> conflict-free ds_read_b128.
// OMODE 0: write split output (Yh, Yl).  OMODE 1: write fp32 Y.
// ---------------------------------------------------------------------------
template<int OMODE>
__global__ __launch_bounds__(256, 3) void gemm_kernel(
    const unsigned short* __restrict__ Ah, const unsigned short* __restrict__ Al,
    const unsigned short* __restrict__ Bh, const unsigned short* __restrict__ Bl,
    const float* __restrict__ bias, float scale,
    float* __restrict__ Y32, unsigned short* __restrict__ Yh, unsigned short* __restrict__ Yl)
{
    __shared__ __align__(16) unsigned short smem[2][8192];   // 32 KB: 2 bufs x (AsH+AsL)

    const int tid  = threadIdx.x;
    const int m0   = blockIdx.x * 128;
    const int n0   = blockIdx.y * 128;
    const int wave = tid >> 6, lane = tid & 63;
    const int wm   = (wave & 1) * 64, wn = (wave >> 1) * 64;
    const int fr   = lane & 15;
    const int kq   = (lane >> 4) * 8;                        // linear k offset (global)
    const int kqs  = (((lane >> 4) ^ ((fr >> 1) & 3)) * 8);  // swizzled k offset (LDS)

    // A staging: wave w -> plane w>>1, rows (w&1)*64 .. +63
    const int lrow  = lane >> 2;                     // 0..15
    const int gd    = (lane & 3) ^ ((lane >> 3) & 3);
    const int rhalf = (wave & 1) * 64;
    const unsigned short* asrc = ((wave >> 1) ? Al : Ah)
                                 + (size_t)(m0 + rhalf + lrow) * E_ + 8 * gd;
    const int ltoff = (wave >> 1) * 4096 + rhalf * 32;   // ushort offset within buf

    // B fragment base pointers (direct global)
    const unsigned short* bhp = Bh + (size_t)(n0 + wn + fr) * E_ + kq;
    const unsigned short* blp = Bl + (size_t)(n0 + wn + fr) * E_ + kq;

    f32x4 acc[4][4] = {};

    // prologue: stage A K-tile 0 into buf 0
    #pragma unroll
    for (int i = 0; i < 4; ++i)
        gload16(asrc + (size_t)i * 16 * E_, &smem[0][ltoff + i * 512]);

    const int NT = E_ / 32;   // 24
    for (int t = 0; t < NT; ++t) {
        const int k0  = t * 32;
        const int cur = t & 1;
        __syncthreads();   // buf[cur] staged & visible; prev reads retired

        // B fragments direct from global (L2-resident weight)
        bf16x8 b_h[4], b_l[4];
        #pragma unroll
        for (int u = 0; u < 4; ++u) {
            b_h[u] = *(const bf16x8*)(bhp + k0 + (size_t)u * 16 * E_);
            b_l[u] = *(const bf16x8*)(blp + k0 + (size_t)u * 16 * E_);
        }
        __builtin_amdgcn_sched_barrier(0);   // pin B-loads before A-prefetch issue

        // prefetch A K-tile t+1 into buf[cur^1]
        if (t + 1 < NT) {
            #pragma unroll
            for (int i = 0; i < 4; ++i)
                gload16(asrc + k0 + 32 + (size_t)i * 16 * E_,
                        &smem[cur ^ 1][ltoff + i * 512]);
        }

        // A fragments from LDS (swizzled, conflict-free)
        const unsigned short* AsH = smem[cur];
        const unsigned short* AsL = smem[cur] + 4096;
        bf16x8 a_h[4], a_l[4];
        #pragma unroll
        for (int u = 0; u < 4; ++u) {
            a_h[u] = *(const bf16x8*)&AsH[(wm + u * 16 + fr) * 32 + kqs];
            a_l[u] = *(const bf16x8*)&AsL[(wm + u * 16 + fr) * 32 + kqs];
        }

        #pragma unroll
        for (int i = 0; i < 4; ++i)
            #pragma unroll
            for (int j = 0; j < 4; ++j) {
                acc[i][j] = __builtin_amdgcn_mfma_f32_16x16x32_bf16(a_h[i], b_h[j], acc[i][j], 0, 0, 0);
                acc[i][j] = __builtin_amdgcn_mfma_f32_16x16x32_bf16(a_h[i], b_l[j], acc[i][j], 0, 0, 0);
                acc[i][j] = __builtin_amdgcn_mfma_f32_16x16x32_bf16(a_l[i], b_h[j], acc[i][j], 0, 0, 0);
            }
    }

    // ---- epilogue: per-wave LDS repack -> wide coalesced stores ----
    float* rep = (float*)&smem[0][0] + wave * 1024;   // [16][64] per wave, 16 KB total
    const int mr = lane >> 2;
    const int nc = (lane & 3) * 16;
    #pragma unroll
    for (int ti = 0; ti < 4; ++ti) {
        __syncthreads();
        #pragma unroll
        for (int tj = 0; tj < 4; ++tj)
            #pragma unroll
            for (int r = 0; r < 4; ++r)
                rep[((lane >> 4) * 4 + r) * 64 + tj * 16 + fr] = acc[ti][tj][r];
        __syncthreads();
        float v[16];
        #pragma unroll
        for (int c = 0; c < 4; ++c)
            *(float4*)&v[4 * c] = *(const float4*)&rep[mr * 64 + nc + 4 * c];
        const int gm = m0 + wm + ti * 16 + mr;
        const int gn = n0 + wn + nc;
        if constexpr (OMODE == 1) {
            #pragma unroll
            for (int c = 0; c < 4; ++c) {
                float4 bv = *(const float4*)&bias[gn + 4 * c];
                float4 o;
                o.x = (v[4*c+0] + bv.x) * scale; o.y = (v[4*c+1] + bv.y) * scale;
                o.z = (v[4*c+2] + bv.z) * scale; o.w = (v[4*c+3] + bv.w) * scale;
                *(float4*)&Y32[(size_t)gm * E_ + gn + 4 * c] = o;
            }
        } else {
            unsigned short hh[16], ll[16];
            #pragma unroll
            for (int c = 0; c < 4; ++c) {
                float4 bv = *(const float4*)&bias[gn + 4 * c];
                HL e0 = split2((v[4*c+0] + bv.x) * scale);
                HL e1 = split2((v[4*c+1] + bv.y) * scale);
                HL e2 = split2((v[4*c+2] + bv.z) * scale);
                HL e3 = split2((v[4*c+3] + bv.w) * scale);
                hh[4*c+0] = e0.h; ll[4*c+0] = e0.l;
                hh[4*c+1] = e1.h; ll[4*c+1] = e1.l;
                hh[4*c+2] = e2.h; ll[4*c+2] = e2.l;
                hh[4*c+3] = e3.h; ll[4*c+3] = e3.l;
            }
            u16x8 H0, H1, L0, L1;
            #pragma unroll
            for (int j = 0; j < 8; ++j) { H0[j] = hh[j]; H1[j] = hh[8+j]; L0[j] = ll[j]; L1[j] = ll[8+j]; }
            *(u16x8*)&Yh[(size_t)gm * E_ + gn]     = H0;
            *(u16x8*)&Yh[(size_t)gm * E_ + gn + 8] = H1;
            *(u16x8*)&Yl[(size_t)gm * E_ + gn]     = L0;
            *(u16x8*)&Yl[(size_t)gm * E_ + gn + 8] = L1;
        }
    }
}

// ---------------------------------------------------------------------------
// Pooled attention logits, split-K over rows: part[rc,h,i,j] =
//   sum_{r in chunk rc} sum_d q[r,i,h,d] * k[r,j,h,d]
// 128x128 (i,j) tile per block, K-chunk = 16 rows * 64 d = 1024 (32 steps).
// Same R4 structure as gemm_kernel: Q staged in LDS (dbuf, swizzled),
// K fragments loaded direct global->VGPR (L3-resident, 2x reuse).
// ---------------------------------------------------------------------------
__global__ __launch_bounds__(256, 2) void attn_mfma(
    const unsigned short* __restrict__ Qh, const unsigned short* __restrict__ Ql,
    const unsigned short* __restrict__ Kh, const unsigned short* __restrict__ Kl,
    float* __restrict__ part)
{
    __shared__ __align__(16) unsigned short smem[2][8192];

    const int tid  = threadIdx.x;
    const int i0   = blockIdx.x * 128;
    const int j0   = blockIdx.y * 128;
    const int hz   = blockIdx.z;          // h * RS_ + rc
    const int h    = hz >> 3;
    const int rc   = hz & 7;
    const int wave = tid >> 6, lane = tid & 63;
    const int wm   = (wave & 1) * 64, wn = (wave >> 1) * 64;
    const int fr   = lane & 15;
    const int kq   = (lane >> 4) * 8;
    const int kqs  = (((lane >> 4) ^ ((fr >> 1) & 3)) * 8);

    const int lrow  = lane >> 2;
    const int gd    = (lane & 3) ^ ((lane >> 3) & 3);
    const int rhalf = (wave & 1) * 64;
    const unsigned short* qsrc = ((wave >> 1) ? Ql : Qh)
        + ((size_t)(rc * 16 * C_) + i0 + rhalf + lrow) * E_ + h * DK_ + 8 * gd;
    const int ltoff = (wave >> 1) * 4096 + rhalf * 32;

    const unsigned short* khp = Kh
        + ((size_t)(rc * 16 * C_) + j0 + wn + fr) * E_ + h * DK_ + kq;
    const unsigned short* klp = Kl
        + ((size_t)(rc * 16 * C_) + j0 + wn + fr) * E_ + h * DK_ + kq;

    f32x4 acc[4][4] = {};

    // prologue: stage Q step 0 into buf 0
    #pragma unroll
    for (int i = 0; i < 4; ++i)
        gload16(qsrc + (size_t)i * 16 * E_, &smem[0][ltoff + i * 512]);

    for (int t = 0; t < 32; ++t) {
        const size_t soff = (size_t)(t >> 1) * C_ * E_ + (t & 1) * 32;
        const int cur = t & 1;
        __syncthreads();

        bf16x8 b_h[4], b_l[4];
        #pragma unroll
        for (int u = 0; u < 4; ++u) {
            b_h[u] = *(const bf16x8*)(khp + soff + (size_t)u * 16 * E_);
            b_l[u] = *(const bf16x8*)(klp + soff + (size_t)u * 16 * E_);
        }
        __builtin_amdgcn_sched_barrier(0);

        if (t + 1 < 32) {
            const size_t snoff = (size_t)((t + 1) >> 1) * C_ * E_ + ((t + 1) & 1) * 32;
            #pragma unroll
            for (int i = 0; i < 4; ++i)
                gload16(qsrc + snoff + (size_t)i * 16 * E_,
                        &smem[cur ^ 1][ltoff + i * 512]);
        }

        const unsigned short* AsH = smem[cur];
        const unsigned short* AsL = smem[cur] + 4096;
        bf16x8 a_h[4], a_l[4];
        #pragma unroll
        for (int u = 0; u < 4; ++u) {
            a_h[u] = *(const bf16x8*)&AsH[(wm + u * 16 + fr) * 32 + kqs];
            a_l[u] = *(const bf16x8*)&AsL[(wm + u * 16 + fr) * 32 + kqs];
        }

        #pragma unroll
        for (int i = 0; i < 4; ++i)
            #pragma unroll
            for (int j = 0; j < 4; ++j) {
                acc[i][j] = __builtin_amdgcn_mfma_f32_16x16x32_bf16(a_h[i], b_h[j], acc[i][j], 0, 0, 0);
                acc[i][j] = __builtin_amdgcn_mfma_f32_16x16x32_bf16(a_h[i], b_l[j], acc[i][j], 0, 0, 0);
                acc[i][j] = __builtin_amdgcn_mfma_f32_16x16x32_bf16(a_l[i], b_h[j], acc[i][j], 0, 0, 0);
            }
    }

    float* rep = (float*)&smem[0][0] + wave * 1024;
    const int mr = lane >> 2;
    const int nc = (lane & 3) * 16;
    #pragma unroll
    for (int ti = 0; ti < 4; ++ti) {
        __syncthreads();
        #pragma unroll
        for (int tj = 0; tj < 4; ++tj)
            #pragma unroll
            for (int r = 0; r < 4; ++r)
                rep[((lane >> 4) * 4 + r) * 64 + tj * 16 + fr] = acc[ti][tj][r];
        __syncthreads();
        const int gi = i0 + wm + ti * 16 + mr;
        const int gj = j0 + wn + nc;
        #pragma unroll
        for (int c = 0; c < 4; ++c) {
            float4 o = *(const float4*)&rep[mr * 64 + nc + 4 * c];
            *(float4*)&part[((size_t)(rc * H_ + h) * C_ + gi) * C_ + gj + 4 * c] = o;
        }
    }
}

// ---------------------------------------------------------------------------
// Reduce RS_ partials + row softmax + write fp32 probs and bf16 split.
// One 256-thread block per (h, i) row.
// ---------------------------------------------------------------------------
__global__ __launch_bounds__(256) void softmax_split(
    const float* __restrict__ part, float* __restrict__ probs,
    unsigned short* __restrict__ ph, unsigned short* __restrict__ pl)
{
    const int row = blockIdx.x;            // h * C_ + i
    const int j = threadIdx.x;
    const int wave = j >> 6, lane = j & 63;

    float s = 0.0f;
    #pragma unroll
    for (int rcn = 0; rcn < RS_; ++rcn)
        s += part[((size_t)rcn * H_ * C_ + row) * C_ + j];

    float m = s;
    #pragma unroll
    for (int off = 32; off > 0; off >>= 1)
        m = fmaxf(m, __shfl_down(m, off, 64));
    __shared__ float redm[4];
    if (lane == 0) redm[wave] = m;
    __syncthreads();
    m = fmaxf(fmaxf(redm[0], redm[1]), fmaxf(redm[2], redm[3]));

    float e = expf(s - m);
    float t = e;
    #pragma unroll
    for (int off = 32; off > 0; off >>= 1)
        t += __shfl_down(t, off, 64);
    __shared__ float reds[4];
    if (lane == 0) reds[wave] = t;
    __syncthreads();
    t = reds[0] + reds[1] + reds[2] + reds[3];

    float p = e / t;
    probs[(size_t)row * C_ + j] = p;
    HL sp = split2(p);
    ph[(size_t)row * C_ + j] = sp.h;
    pl[(size_t)row * C_ + j] = sp.l;
}

// ---------------------------------------------------------------------------
// Context: C[r*C+i, h*64+d] = sum_j P[h,i,j] * V[r*C+j, h*64+d], split output.
// Per (i-block, r, h): M=128(i), N=64(d), K=256(j), BK=32 -> 8 steps.
// V staged transposed into LDS ([d][j]).  (Unchanged this round.)
// ---------------------------------------------------------------------------
__global__ __launch_bounds__(256, 2) void ctx_mfma(
    const unsigned short* __restrict__ Ph, const unsigned short* __restrict__ Pl,
    const unsigned short* __restrict__ Vh, const unsigned short* __restrict__ Vl,
    unsigned short* __restrict__ Ch, unsigned short* __restrict__ Cl)
{
    __shared__ __align__(16) unsigned short smem[15360];   // 30 KB
    unsigned short* PsH = smem;            // [128][LP]
    unsigned short* PsL = smem + 5120;
    unsigned short* VsH = smem + 10240;    // [64][LP]
    unsigned short* VsL = smem + 12800;

    const int tid  = threadIdx.x;
    const int i0   = blockIdx.x * 128;
    const int r    = blockIdx.y;
    const int h    = blockIdx.z;
    const int wave = tid >> 6, lane = tid & 63;
    const int wm   = (wave & 1) * 64, wn = (wave >> 1) * 32;
    const int fr   = lane & 15;
    const int kq   = (lane >> 4) * 8;
    const int srow = tid >> 1;
    const int sk   = (tid & 1) * 16;
    const int vjj  = tid & 31;
    const int vdg  = tid >> 5;             // 0..7

    f32x4 acc[4][2] = {};

    for (int s = 0; s < 8; ++s) {
        const int jb = s * 32;
        const size_t pb = ((size_t)(h * C_) + i0 + srow) * C_ + jb + sk;
        *(u16x8*)&PsH[srow * LP + sk]     = *(const u16x8*)&Ph[pb];
        *(u16x8*)&PsH[srow * LP + sk + 8] = *(const u16x8*)&Ph[pb + 8];
        *(u16x8*)&PsL[srow * LP + sk]     = *(const u16x8*)&Pl[pb];
        *(u16x8*)&PsL[srow * LP + sk + 8] = *(const u16x8*)&Pl[pb + 8];
        const size_t vb = ((size_t)(r * C_) + jb + vjj) * E_ + h * DK_ + vdg * 8;
        u16x8 v_h = *(const u16x8*)&Vh[vb];
        u16x8 v_l = *(const u16x8*)&Vl[vb];
        #pragma unroll
        for (int u = 0; u < 8; ++u) {
            VsH[(vdg * 8 + u) * LP + vjj] = v_h[u];
            VsL[(vdg * 8 + u) * LP + vjj] = v_l[u];
        }
        __syncthreads();

        bf16x8 p_h[4], p_l[4], w_h[2], w_l[2];
        #pragma unroll
        for (int t = 0; t < 4; ++t) {
            p_h[t] = *(const bf16x8*)&PsH[(wm + t * 16 + fr) * LP + kq];
            p_l[t] = *(const bf16x8*)&PsL[(wm + t * 16 + fr) * LP + kq];
        }
        #pragma unroll
        for (int t = 0; t < 2; ++t) {
            w_h[t] = *(const bf16x8*)&VsH[(wn + t * 16 + fr) * LP + kq];
            w_l[t] = *(const bf16x8*)&VsL[(wn + t * 16 + fr) * LP + kq];
        }
        #pragma unroll
        for (int i = 0; i < 4; ++i)
            #pragma unroll
            for (int j = 0; j < 2; ++j) {
                acc[i][j] = __builtin_amdgcn_mfma_f32_16x16x32_bf16(p_h[i], w_h[j], acc[i][j], 0, 0, 0);
                acc[i][j] = __builtin_amdgcn_mfma_f32_16x16x32_bf16(p_h[i], w_l[j], acc[i][j], 0, 0, 0);
                acc[i][j] = __builtin_amdgcn_mfma_f32_16x16x32_bf16(p_l[i], w_h[j], acc[i][j], 0, 0, 0);
            }
        __syncthreads();
    }

    float* rep = (float*)smem + wave * 512;   // [16][32] per wave
    const int mr = lane >> 2;
    const int nc = (lane & 3) * 8;
    #pragma unroll
    for (int ti = 0; ti < 4; ++ti) {
        __syncthreads();
        #pragma unroll
        for (int tj = 0; tj < 2; ++tj)
            #pragma unroll
            for (int rr = 0; rr < 4; ++rr)
                rep[((lane >> 4) * 4 + rr) * 32 + tj * 16 + fr] = acc[ti][tj][rr];
        __syncthreads();
        float v[8];
        *(float4*)&v[0] = *(const float4*)&rep[mr * 32 + nc];
        *(float4*)&v[4] = *(const float4*)&rep[mr * 32 + nc + 4];
        const int gm = r * C_ + i0 + wm + ti * 16 + mr;
        const int gn = h * DK_ + wn + nc;
        u16x8 H8, L8;
        #pragma unroll
        for (int jj = 0; jj < 8; ++jj) { HL e = split2(v[jj]); H8[jj] = e.h; L8[jj] = e.l; }
        *(u16x8*)&Ch[(size_t)gm * E_ + gn] = H8;
        *(u16x8*)&Cl[(size_t)gm * E_ + gn] = L8;
    }
}

// ---------------------------------------------------------------------------
extern "C" void kernel_launch(void* const* d_in, const int* in_sizes, int n_in,
                              void* d_out, int out_size, void* d_ws, size_t ws_size,
                              hipStream_t stream)
{
    (void)in_sizes; (void)n_in; (void)out_size; (void)ws_size;

    const float* x  = (const float*)d_in[0];
    const float* Wq = (const float*)d_in[1];
    const float* bq = (const float*)d_in[2];
    const float* Wk = (const float*)d_in[3];
    const float* bk = (const float*)d_in[4];
    const float* Wv = (const float*)d_in[5];
    const float* bv = (const float*)d_in[6];
    const float* Wo = (const float*)d_in[7];
    const float* bo = (const float*)d_in[8];

    float* out   = (float*)d_out;
    float* probs = out + (size_t)T_ * E_;
    float* part  = out;                     // scratch: out region free until attn

    // ws: 6 planar bf16 buffers of T_*E_ ushorts = 302 MB (unchanged).
    const size_t QN = (size_t)T_ * E_;
    const size_t WN = (size_t)E_ * E_;
    unsigned short* qh = (unsigned short*)d_ws;
    unsigned short* ql = qh + QN;
    unsigned short* kh = ql + QN;
    unsigned short* kl = kh + QN;
    unsigned short* vh = kl + QN;
    unsigned short* vl = vh + QN;
    unsigned short* ph = kh;                 // reuse kh plane (dead after attn)
    unsigned short* pl = kh + (size_t)H_ * C_ * C_;
    unsigned short* ch = qh;                 // reuse q planes (dead after attn)
    unsigned short* cl = ql;

    // Scratch overlays (no new workspace):
    //   xh/xl   -> out region [0, 100.7 MB): dead before attn writes `part`.
    //   wsph/l  -> probs tail region (3.1 MB): dead before softmax writes probs.
    //   woh/wol -> kl plane: dead after attn, survives softmax/ctx/gemm4.
    unsigned short* xh   = (unsigned short*)out;
    unsigned short* xl   = xh + QN;
    unsigned short* wsph = (unsigned short*)probs;
    unsigned short* wspl = wsph + WN;
    unsigned short* woh  = kl;
    unsigned short* wol  = kl + WN;

    const float scaling = 0.125f / sqrtf(128.0f);   // DK^-0.5 / sqrt(R)

    dim3 blk(256);
    const int xblocks = (int)(QN / 2048);   // 8 elems/thread, exact
    const int wblocks = (int)(WN / 2048);

    split_kernel<<<dim3(xblocks), blk, 0, stream>>>(x, xh, xl);

    split_kernel<<<dim3(wblocks), blk, 0, stream>>>(Wq, wsph, wspl);
    gemm_kernel<0><<<dim3(T_ / 128, E_ / 128), blk, 0, stream>>>(
        xh, xl, wsph, wspl, bq, scaling, nullptr, qh, ql);

    split_kernel<<<dim3(wblocks), blk, 0, stream>>>(Wk, wsph, wspl);
    gemm_kernel<0><<<dim3(T_ / 128, E_ / 128), blk, 0, stream>>>(
        xh, xl, wsph, wspl, bk, 1.0f, nullptr, kh, kl);

    split_kernel<<<dim3(wblocks), blk, 0, stream>>>(Wv, wsph, wspl);
    gemm_kernel<0><<<dim3(T_ / 128, E_ / 128), blk, 0, stream>>>(
        xh, xl, wsph, wspl, bv, 1.0f, nullptr, vh, vl);

    attn_mfma<<<dim3(C_ / 128, C_ / 128, H_ * RS_), blk, 0, stream>>>(qh, ql, kh, kl, part);

    split_kernel<<<dim3(wblocks), blk, 0, stream>>>(Wo, woh, wol);   // kl plane now dead

    softmax_split<<<dim3(H_ * C_), blk, 0, stream>>>(part, probs, ph, pl);
    ctx_mfma<<<dim3(C_ / 128, R_, H_), blk, 0, stream>>>(ph, pl, vh, vl, ch, cl);

    gemm_kernel<1><<<dim3(T_ / 128, E_ / 128), blk, 0, stream>>>(
        ch, cl, woh, wol, bo, 1.0f, out, nullptr, nullptr);
}

// Round 5
// 987.275 us; speedup vs baseline: 1.2085x; 1.2085x over previous
//
#include <hip/hip_runtime.h>
#include <math.h>

// Problem constants
#define R_  128
#define C_  256
#define E_  768
#define H_  12
#define DK_ 64
#define T_  (R_*C_)       // 32768 tokens
#define RS_ 8             // split-K over rows in attn kernel
#define LP  40            // LDS pitch for ctx_mfma only (legacy padded layout)

typedef __attribute__((ext_vector_type(8))) short          bf16x8;
typedef __attribute__((ext_vector_type(4))) float          f32x4;
typedef __attribute__((ext_vector_type(4))) unsigned short u16x4;
typedef __attribute__((ext_vector_type(8))) unsigned short u16x8;

struct HL { unsigned short h, l; };

// fp32 -> (hi, lo) bf16 split via truncation. hi+lo represents f with ~2^-16
// relative error; lo = f - hi is exact in fp32 (Sterbenz), then truncated.
__device__ __forceinline__ HL split2(float f) {
    HL o;
    unsigned int u = __float_as_uint(f);
    o.h = (unsigned short)(u >> 16);
    float r = f - __uint_as_float(u & 0xFFFF0000u);
    o.l = (unsigned short)(__float_as_uint(r) >> 16);
    return o;
}

// async global->LDS, 16 B per lane. LDS dest is wave-uniform base + lane*16.
__device__ __forceinline__ void gload16(const void* g, void* l) {
    __builtin_amdgcn_global_load_lds(
        (const __attribute__((address_space(1))) unsigned int*)g,
        (__attribute__((address_space(3))) unsigned int*)l,
        16, 0, 0);
}

// ---------------------------------------------------------------------------
// Pre-split: fp32 -> planar (hi, lo) bf16. 8 elems/thread, exact grids only.
// (Used only for x now; weights are split in-kernel during B staging.)
// ---------------------------------------------------------------------------
__global__ __launch_bounds__(256) void split_kernel(
    const float* __restrict__ src,
    unsigned short* __restrict__ h, unsigned short* __restrict__ l)
{
    const size_t i = ((size_t)blockIdx.x * 256 + threadIdx.x) * 8;
    float4 f0 = *(const float4*)(src + i);
    float4 f1 = *(const float4*)(src + i + 4);
    float v[8] = { f0.x, f0.y, f0.z, f0.w, f1.x, f1.y, f1.z, f1.w };
    u16x8 hh, ll;
    #pragma unroll
    for (int j = 0; j < 8; ++j) { HL e = split2(v[j]); hh[j] = e.h; ll[j] = e.l; }
    *(u16x8*)(h + i) = hh;
    *(u16x8*)(l + i) = ll;
}

// ---------------------------------------------------------------------------
// Fused GEMM: Y_sel[m,n] = (sum_k A[m,k]*W_sel[n,k] + b_sel[n]) * scale_sel
// A pre-split planar bf16 (Ah/Al); W fp32, split in-kernel during staging.
// blockIdx.y in [0, 6*NW): sel = y/6 picks {W,b,scale,output}, n0 = (y%6)*128.
// QKV: NW=3 in one launch -> A streams through L3 ONCE for all three.
//
// Inner loop = R2-proven structure (best measured: 138 us/GEMM-equiv):
// 128x128 block tile, BK=32, 4 waves (2x2 of 64x64), dbuf LDS, ONE
// __syncthreads per K-step (its implicit vmcnt/lgkm drain is the pipeline
// fence), mfma_f32_16x16x32_bf16 with 3-term hi/lo product.
//  - A: 2 planes staged via gload16 (wave w -> plane w>>1, rows (w&1)*64..+63),
//    granule swizzle g^((r>>1)&3) realized by permuting the per-lane GLOBAL
//    source address (LDS dest linear, as gload_lds requires).
//  - B: fp32 weight rows loaded to regs, split2'd, ds_write'd with the SAME
//    slot swizzle (R0's proven B-path; same LDS/HBM bytes as pre-split bf16,
//    VALU cost hides on the separate pipe).
//  - reads XOR the same term -> conflict-free ds_read_b128.
// OMODE 0: write split outputs (Ysel_h/l).  OMODE 1: write fp32 Y32.
// ---------------------------------------------------------------------------
template<int OMODE>
__global__ __launch_bounds__(256, 2) void gemm_fused(
    const unsigned short* __restrict__ Ah, const unsigned short* __restrict__ Al,
    const float* __restrict__ W0, const float* __restrict__ W1, const float* __restrict__ W2,
    const float* __restrict__ b0, const float* __restrict__ b1, const float* __restrict__ b2,
    float qscale, float* __restrict__ Y32,
    unsigned short* __restrict__ Y0h, unsigned short* __restrict__ Y0l,
    unsigned short* __restrict__ Y1h, unsigned short* __restrict__ Y1l,
    unsigned short* __restrict__ Y2h, unsigned short* __restrict__ Y2l)
{
    __shared__ __align__(16) unsigned short smem[2][16384];  // per buf: AsH|AsL|BsH|BsL

    const int tid = threadIdx.x;
    const int m0  = blockIdx.x * 128;
    const int yb  = blockIdx.y;
    const int sel = yb / 6;
    const int n0  = (yb % 6) * 128;

    const float* Wsel = (sel == 0) ? W0 : (sel == 1) ? W1 : W2;
    const float* bsel = (sel == 0) ? b0 : (sel == 1) ? b1 : b2;
    const float  scl  = (sel == 0) ? qscale : 1.0f;
    unsigned short* Yh = (sel == 0) ? Y0h : (sel == 1) ? Y1h : Y2h;
    unsigned short* Yl = (sel == 0) ? Y0l : (sel == 1) ? Y1l : Y2l;

    const int wave = tid >> 6, lane = tid & 63;
    const int wm = (wave & 1) * 64, wn = (wave >> 1) * 64;
    const int fr = lane & 15;
    const int kqs = (((lane >> 4) ^ ((fr >> 1) & 3)) * 8);   // swizzled read offset

    // A staging: wave w -> plane w>>1, rows (w&1)*64..+63, 4x gload16 each
    const int lrow   = lane >> 2;
    const int gd     = (lane & 3) ^ ((lane >> 3) & 3);
    const int aplane = wave >> 1;
    const int rhalf  = (wave & 1) * 64;
    const unsigned short* asrc = (aplane ? Al : Ah)
                                 + (size_t)(m0 + rhalf + lrow) * E_ + 8 * gd;
    const int ltoff = aplane * 4096 + rhalf * 32;

    // B staging: thread -> row tid>>1, granules (tid&1)*2, +1 (8 fp32 each)
    const int srow  = tid >> 1;
    const int g0    = (tid & 1) * 2;
    const float* wrow = Wsel + (size_t)(n0 + srow) * E_ + g0 * 8;
    const int slot0 = (g0)     ^ ((srow >> 1) & 3);
    const int slot1 = (g0 + 1) ^ ((srow >> 1) & 3);
    const int bbase = srow * 32;

    auto stageB = [&](int buf, int k0) {
        float4 f0 = *(const float4*)(wrow + k0);
        float4 f1 = *(const float4*)(wrow + k0 + 4);
        float4 f2 = *(const float4*)(wrow + k0 + 8);
        float4 f3 = *(const float4*)(wrow + k0 + 12);
        float va[8] = { f0.x, f0.y, f0.z, f0.w, f1.x, f1.y, f1.z, f1.w };
        float vb[8] = { f2.x, f2.y, f2.z, f2.w, f3.x, f3.y, f3.z, f3.w };
        u16x8 h0, l0, h1, l1;
        #pragma unroll
        for (int j = 0; j < 8; ++j) { HL e = split2(va[j]); h0[j] = e.h; l0[j] = e.l; }
        #pragma unroll
        for (int j = 0; j < 8; ++j) { HL e = split2(vb[j]); h1[j] = e.h; l1[j] = e.l; }
        *(u16x8*)&smem[buf][8192  + bbase + slot0 * 8] = h0;
        *(u16x8*)&smem[buf][12288 + bbase + slot0 * 8] = l0;
        *(u16x8*)&smem[buf][8192  + bbase + slot1 * 8] = h1;
        *(u16x8*)&smem[buf][12288 + bbase + slot1 * 8] = l1;
    };

    f32x4 acc[4][4] = {};

    // prologue: stage K-tile 0 into buf 0 (A via gload, B via reg-split)
    #pragma unroll
    for (int i = 0; i < 4; ++i)
        gload16(asrc + (size_t)i * 16 * E_, &smem[0][ltoff + i * 512]);
    stageB(0, 0);

    const int NT = E_ / 32;   // 24
    for (int t = 0; t < NT; ++t) {
        const int cur = t & 1;
        __syncthreads();   // buf[cur] staged & visible; prev reads retired

        if (t + 1 < NT) {
            const int k1 = (t + 1) * 32;
            #pragma unroll
            for (int i = 0; i < 4; ++i)
                gload16(asrc + k1 + (size_t)i * 16 * E_,
                        &smem[cur ^ 1][ltoff + i * 512]);
            stageB(cur ^ 1, k1);
        }

        const unsigned short* AsH = smem[cur];
        const unsigned short* AsL = smem[cur] + 4096;
        const unsigned short* BsH = smem[cur] + 8192;
        const unsigned short* BsL = smem[cur] + 12288;

        bf16x8 a_h[4], a_l[4], b_h[4], b_l[4];
        #pragma unroll
        for (int u = 0; u < 4; ++u) {
            a_h[u] = *(const bf16x8*)&AsH[(wm + u * 16 + fr) * 32 + kqs];
            a_l[u] = *(const bf16x8*)&AsL[(wm + u * 16 + fr) * 32 + kqs];
            b_h[u] = *(const bf16x8*)&BsH[(wn + u * 16 + fr) * 32 + kqs];
            b_l[u] = *(const bf16x8*)&BsL[(wn + u * 16 + fr) * 32 + kqs];
        }
        #pragma unroll
        for (int i = 0; i < 4; ++i)
            #pragma unroll
            for (int j = 0; j < 4; ++j) {
                acc[i][j] = __builtin_amdgcn_mfma_f32_16x16x32_bf16(a_h[i], b_h[j], acc[i][j], 0, 0, 0);
                acc[i][j] = __builtin_amdgcn_mfma_f32_16x16x32_bf16(a_h[i], b_l[j], acc[i][j], 0, 0, 0);
                acc[i][j] = __builtin_amdgcn_mfma_f32_16x16x32_bf16(a_l[i], b_h[j], acc[i][j], 0, 0, 0);
            }
    }

    // ---- epilogue: per-wave LDS repack -> wide coalesced stores ----
    float* rep = (float*)&smem[0][0] + wave * 1024;   // [16][64] per wave
    const int mr = lane >> 2;
    const int nc = (lane & 3) * 16;
    #pragma unroll
    for (int ti = 0; ti < 4; ++ti) {
        __syncthreads();
        #pragma unroll
        for (int tj = 0; tj < 4; ++tj)
            #pragma unroll
            for (int r = 0; r < 4; ++r)
                rep[((lane >> 4) * 4 + r) * 64 + tj * 16 + fr] = acc[ti][tj][r];
        __syncthreads();
        float v[16];
        #pragma unroll
        for (int c = 0; c < 4; ++c)
            *(float4*)&v[4 * c] = *(const float4*)&rep[mr * 64 + nc + 4 * c];
        const int gm = m0 + wm + ti * 16 + mr;
        const int gn = n0 + wn + nc;
        if constexpr (OMODE == 1) {
            #pragma unroll
            for (int c = 0; c < 4; ++c) {
                float4 bv = *(const float4*)&bsel[gn + 4 * c];
                float4 o;
                o.x = (v[4*c+0] + bv.x) * scl; o.y = (v[4*c+1] + bv.y) * scl;
                o.z = (v[4*c+2] + bv.z) * scl; o.w = (v[4*c+3] + bv.w) * scl;
                *(float4*)&Y32[(size_t)gm * E_ + gn + 4 * c] = o;
            }
        } else {
            unsigned short hh[16], ll[16];
            #pragma unroll
            for (int c = 0; c < 4; ++c) {
                float4 bv = *(const float4*)&bsel[gn + 4 * c];
                HL e0 = split2((v[4*c+0] + bv.x) * scl);
                HL e1 = split2((v[4*c+1] + bv.y) * scl);
                HL e2 = split2((v[4*c+2] + bv.z) * scl);
                HL e3 = split2((v[4*c+3] + bv.w) * scl);
                hh[4*c+0] = e0.h; ll[4*c+0] = e0.l;
                hh[4*c+1] = e1.h; ll[4*c+1] = e1.l;
                hh[4*c+2] = e2.h; ll[4*c+2] = e2.l;
                hh[4*c+3] = e3.h; ll[4*c+3] = e3.l;
            }
            u16x8 H0, H1, L0, L1;
            #pragma unroll
            for (int j = 0; j < 8; ++j) { H0[j] = hh[j]; H1[j] = hh[8+j]; L0[j] = ll[j]; L1[j] = ll[8+j]; }
            *(u16x8*)&Yh[(size_t)gm * E_ + gn]     = H0;
            *(u16x8*)&Yh[(size_t)gm * E_ + gn + 8] = H1;
            *(u16x8*)&Yl[(size_t)gm * E_ + gn]     = L0;
            *(u16x8*)&Yl[(size_t)gm * E_ + gn + 8] = L1;
        }
    }
}

// ---------------------------------------------------------------------------
// Pooled attention logits, split-K over rows: part[rc,h,i,j] =
//   sum_{r in chunk rc} sum_d q[r,i,h,d] * k[r,j,h,d]
// 128x128 (i,j) tile per block, K-chunk = 16 rows * 64 d = 1024 (32 steps).
// R2-exact structure: all four planes gload_lds-staged (wave w -> tile w),
// dbuf, one __syncthreads per step.
// ---------------------------------------------------------------------------
__global__ __launch_bounds__(256, 2) void attn_mfma(
    const unsigned short* __restrict__ Qh, const unsigned short* __restrict__ Ql,
    const unsigned short* __restrict__ Kh, const unsigned short* __restrict__ Kl,
    float* __restrict__ part)
{
    __shared__ __align__(16) unsigned short smem[2][16384];

    const int tid  = threadIdx.x;
    const int i0   = blockIdx.x * 128;
    const int j0   = blockIdx.y * 128;
    const int hz   = blockIdx.z;          // h * RS_ + rc
    const int h    = hz >> 3;
    const int rc   = hz & 7;
    const int wave = tid >> 6, lane = tid & 63;
    const int wm   = (wave & 1) * 64, wn = (wave >> 1) * 64;
    const int fr   = lane & 15;
    const int kqs  = (((lane >> 4) ^ ((fr >> 1) & 3)) * 8);

    const int lrow = lane >> 2;
    const int gd   = (lane & 3) ^ ((lane >> 3) & 3);
    const unsigned short* gsrc = (wave == 0) ? Qh : (wave == 1) ? Ql
                               : (wave == 2) ? Kh : Kl;
    const int rbase = (wave < 2) ? i0 : j0;
    const int ltoff = wave * 4096;
    const unsigned short* sp0 =
        gsrc + ((size_t)(rc * 16 * C_) + rbase + lrow) * E_ + h * DK_ + 8 * gd;

    f32x4 acc[4][4] = {};

    // prologue: stage step 0 into buffer 0
    {
        unsigned short* lt = &smem[0][ltoff];
        #pragma unroll
        for (int i = 0; i < 8; ++i)
            gload16(sp0 + (size_t)i * 16 * E_, lt + i * 512);
    }

    int cur = 0;
    for (int s = 0; s < 32; ++s) {
        __syncthreads();
        if (s + 1 < 32) {
            const int sn = s + 1;
            const unsigned short* sp =
                sp0 + (size_t)(sn >> 1) * C_ * E_ + (sn & 1) * 32;
            unsigned short* lt = &smem[cur ^ 1][ltoff];
            #pragma unroll
            for (int i = 0; i < 8; ++i)
                gload16(sp + (size_t)i * 16 * E_, lt + i * 512);
        }
        const unsigned short* AsH = smem[cur];
        const unsigned short* AsL = smem[cur] + 4096;
        const unsigned short* BsH = smem[cur] + 8192;
        const unsigned short* BsL = smem[cur] + 12288;

        bf16x8 a_h[4], a_l[4], b_h[4], b_l[4];
        #pragma unroll
        for (int t = 0; t < 4; ++t) {
            a_h[t] = *(const bf16x8*)&AsH[(wm + t * 16 + fr) * 32 + kqs];
            a_l[t] = *(const bf16x8*)&AsL[(wm + t * 16 + fr) * 32 + kqs];
            b_h[t] = *(const bf16x8*)&BsH[(wn + t * 16 + fr) * 32 + kqs];
            b_l[t] = *(const bf16x8*)&BsL[(wn + t * 16 + fr) * 32 + kqs];
        }
        #pragma unroll
        for (int i = 0; i < 4; ++i)
            #pragma unroll
            for (int j = 0; j < 4; ++j) {
                acc[i][j] = __builtin_amdgcn_mfma_f32_16x16x32_bf16(a_h[i], b_h[j], acc[i][j], 0, 0, 0);
                acc[i][j] = __builtin_amdgcn_mfma_f32_16x16x32_bf16(a_h[i], b_l[j], acc[i][j], 0, 0, 0);
                acc[i][j] = __builtin_amdgcn_mfma_f32_16x16x32_bf16(a_l[i], b_h[j], acc[i][j], 0, 0, 0);
            }
        cur ^= 1;
    }

    float* rep = (float*)&smem[0][0] + wave * 1024;
    const int mr = lane >> 2;
    const int nc = (lane & 3) * 16;
    #pragma unroll
    for (int ti = 0; ti < 4; ++ti) {
        __syncthreads();
        #pragma unroll
        for (int tj = 0; tj < 4; ++tj)
            #pragma unroll
            for (int r = 0; r < 4; ++r)
                rep[((lane >> 4) * 4 + r) * 64 + tj * 16 + fr] = acc[ti][tj][r];
        __syncthreads();
        const int gi = i0 + wm + ti * 16 + mr;
        const int gj = j0 + wn + nc;
        #pragma unroll
        for (int c = 0; c < 4; ++c) {
            float4 o = *(const float4*)&rep[mr * 64 + nc + 4 * c];
            *(float4*)&part[((size_t)(rc * H_ + h) * C_ + gi) * C_ + gj + 4 * c] = o;
        }
    }
}

// ---------------------------------------------------------------------------
// Reduce RS_ partials + row softmax + write fp32 probs and bf16 split.
// One 256-thread block per (h, i) row.
// ---------------------------------------------------------------------------
__global__ __launch_bounds__(256) void softmax_split(
    const float* __restrict__ part, float* __restrict__ probs,
    unsigned short* __restrict__ ph, unsigned short* __restrict__ pl)
{
    const int row = blockIdx.x;            // h * C_ + i
    const int j = threadIdx.x;
    const int wave = j >> 6, lane = j & 63;

    float s = 0.0f;
    #pragma unroll
    for (int rcn = 0; rcn < RS_; ++rcn)
        s += part[((size_t)rcn * H_ * C_ + row) * C_ + j];

    float m = s;
    #pragma unroll
    for (int off = 32; off > 0; off >>= 1)
        m = fmaxf(m, __shfl_down(m, off, 64));
    __shared__ float redm[4];
    if (lane == 0) redm[wave] = m;
    __syncthreads();
    m = fmaxf(fmaxf(redm[0], redm[1]), fmaxf(redm[2], redm[3]));

    float e = expf(s - m);
    float t = e;
    #pragma unroll
    for (int off = 32; off > 0; off >>= 1)
        t += __shfl_down(t, off, 64);
    __shared__ float reds[4];
    if (lane == 0) reds[wave] = t;
    __syncthreads();
    t = reds[0] + reds[1] + reds[2] + reds[3];

    float p = e / t;
    probs[(size_t)row * C_ + j] = p;
    HL sp = split2(p);
    ph[(size_t)row * C_ + j] = sp.h;
    pl[(size_t)row * C_ + j] = sp.l;
}

// ---------------------------------------------------------------------------
// Context: C[r*C+i, h*64+d] = sum_j P[h,i,j] * V[r*C+j, h*64+d], split output.
// Per (i-block, r, h): M=128(i), N=64(d), K=256(j), BK=32 -> 8 steps.
// V staged transposed into LDS ([d][j]).  (Unchanged.)
// ---------------------------------------------------------------------------
__global__ __launch_bounds__(256, 2) void ctx_mfma(
    const unsigned short* __restrict__ Ph, const unsigned short* __restrict__ Pl,
    const unsigned short* __restrict__ Vh, const unsigned short* __restrict__ Vl,
    unsigned short* __restrict__ Ch, unsigned short* __restrict__ Cl)
{
    __shared__ __align__(16) unsigned short smem[15360];   // 30 KB
    unsigned short* PsH = smem;            // [128][LP]
    unsigned short* PsL = smem + 5120;
    unsigned short* VsH = smem + 10240;    // [64][LP]
    unsigned short* VsL = smem + 12800;

    const int tid  = threadIdx.x;
    const int i0   = blockIdx.x * 128;
    const int r    = blockIdx.y;
    const int h    = blockIdx.z;
    const int wave = tid >> 6, lane = tid & 63;
    const int wm   = (wave & 1) * 64, wn = (wave >> 1) * 32;
    const int fr   = lane & 15;
    const int kq   = (lane >> 4) * 8;
    const int srow = tid >> 1;
    const int sk   = (tid & 1) * 16;
    const int vjj  = tid & 31;
    const int vdg  = tid >> 5;             // 0..7

    f32x4 acc[4][2] = {};

    for (int s = 0; s < 8; ++s) {
        const int jb = s * 32;
        const size_t pb = ((size_t)(h * C_) + i0 + srow) * C_ + jb + sk;
        *(u16x8*)&PsH[srow * LP + sk]     = *(const u16x8*)&Ph[pb];
        *(u16x8*)&PsH[srow * LP + sk + 8] = *(const u16x8*)&Ph[pb + 8];
        *(u16x8*)&PsL[srow * LP + sk]     = *(const u16x8*)&Pl[pb];
        *(u16x8*)&PsL[srow * LP + sk + 8] = *(const u16x8*)&Pl[pb + 8];
        const size_t vb = ((size_t)(r * C_) + jb + vjj) * E_ + h * DK_ + vdg * 8;
        u16x8 v_h = *(const u16x8*)&Vh[vb];
        u16x8 v_l = *(const u16x8*)&Vl[vb];
        #pragma unroll
        for (int u = 0; u < 8; ++u) {
            VsH[(vdg * 8 + u) * LP + vjj] = v_h[u];
            VsL[(vdg * 8 + u) * LP + vjj] = v_l[u];
        }
        __syncthreads();

        bf16x8 p_h[4], p_l[4], w_h[2], w_l[2];
        #pragma unroll
        for (int t = 0; t < 4; ++t) {
            p_h[t] = *(const bf16x8*)&PsH[(wm + t * 16 + fr) * LP + kq];
            p_l[t] = *(const bf16x8*)&PsL[(wm + t * 16 + fr) * LP + kq];
        }
        #pragma unroll
        for (int t = 0; t < 2; ++t) {
            w_h[t] = *(const bf16x8*)&VsH[(wn + t * 16 + fr) * LP + kq];
            w_l[t] = *(const bf16x8*)&VsL[(wn + t * 16 + fr) * LP + kq];
        }
        #pragma unroll
        for (int i = 0; i < 4; ++i)
            #pragma unroll
            for (int j = 0; j < 2; ++j) {
                acc[i][j] = __builtin_amdgcn_mfma_f32_16x16x32_bf16(p_h[i], w_h[j], acc[i][j], 0, 0, 0);
                acc[i][j] = __builtin_amdgcn_mfma_f32_16x16x32_bf16(p_h[i], w_l[j], acc[i][j], 0, 0, 0);
                acc[i][j] = __builtin_amdgcn_mfma_f32_16x16x32_bf16(p_l[i], w_h[j], acc[i][j], 0, 0, 0);
            }
        __syncthreads();
    }

    float* rep = (float*)smem + wave * 512;   // [16][32] per wave
    const int mr = lane >> 2;
    const int nc = (lane & 3) * 8;
    #pragma unroll
    for (int ti = 0; ti < 4; ++ti) {
        __syncthreads();
        #pragma unroll
        for (int tj = 0; tj < 2; ++tj)
            #pragma unroll
            for (int rr = 0; rr < 4; ++rr)
                rep[((lane >> 4) * 4 + rr) * 32 + tj * 16 + fr] = acc[ti][tj][rr];
        __syncthreads();
        float v[8];
        *(float4*)&v[0] = *(const float4*)&rep[mr * 32 + nc];
        *(float4*)&v[4] = *(const float4*)&rep[mr * 32 + nc + 4];
        const int gm = r * C_ + i0 + wm + ti * 16 + mr;
        const int gn = h * DK_ + wn + nc;
        u16x8 H8, L8;
        #pragma unroll
        for (int jj = 0; jj < 8; ++jj) { HL e = split2(v[jj]); H8[jj] = e.h; L8[jj] = e.l; }
        *(u16x8*)&Ch[(size_t)gm * E_ + gn] = H8;
        *(u16x8*)&Cl[(size_t)gm * E_ + gn] = L8;
    }
}

// ---------------------------------------------------------------------------
extern "C" void kernel_launch(void* const* d_in, const int* in_sizes, int n_in,
                              void* d_out, int out_size, void* d_ws, size_t ws_size,
                              hipStream_t stream)
{
    (void)in_sizes; (void)n_in; (void)out_size; (void)ws_size;

    const float* x  = (const float*)d_in[0];
    const float* Wq = (const float*)d_in[1];
    const float* bq = (const float*)d_in[2];
    const float* Wk = (const float*)d_in[3];
    const float* bk = (const float*)d_in[4];
    const float* Wv = (const float*)d_in[5];
    const float* bv = (const float*)d_in[6];
    const float* Wo = (const float*)d_in[7];
    const float* bo = (const float*)d_in[8];

    float* out   = (float*)d_out;
    float* probs = out + (size_t)T_ * E_;
    float* part  = out;                     // scratch: out region free until attn

    // ws: 6 planar bf16 buffers of T_*E_ ushorts = 302 MB (unchanged).
    const size_t QN = (size_t)T_ * E_;
    unsigned short* qh = (unsigned short*)d_ws;
    unsigned short* ql = qh + QN;
    unsigned short* kh = ql + QN;
    unsigned short* kl = kh + QN;
    unsigned short* vh = kl + QN;
    unsigned short* vl = vh + QN;
    unsigned short* ph = kh;                 // reuse kh plane (dead after attn)
    unsigned short* pl = kh + (size_t)H_ * C_ * C_;
    unsigned short* ch = qh;                 // reuse q planes (dead after attn)
    unsigned short* cl = ql;

    // x split overlays the out region (dead before attn writes `part`).
    unsigned short* xh = (unsigned short*)out;
    unsigned short* xl = xh + QN;

    const float scaling = 0.125f / sqrtf(128.0f);   // DK^-0.5 / sqrt(R)

    dim3 blk(256);
    const int xblocks = (int)(QN / 2048);   // 8 elems/thread, exact

    split_kernel<<<dim3(xblocks), blk, 0, stream>>>(x, xh, xl);

    // Q, K, V in ONE launch: A (x split) streams through L3 once.
    gemm_fused<0><<<dim3(T_ / 128, 18), blk, 0, stream>>>(
        xh, xl, Wq, Wk, Wv, bq, bk, bv, scaling, nullptr,
        qh, ql, kh, kl, vh, vl);

    attn_mfma<<<dim3(C_ / 128, C_ / 128, H_ * RS_), blk, 0, stream>>>(qh, ql, kh, kl, part);
    softmax_split<<<dim3(H_ * C_), blk, 0, stream>>>(part, probs, ph, pl);
    ctx_mfma<<<dim3(C_ / 128, R_, H_), blk, 0, stream>>>(ph, pl, vh, vl, ch, cl);

    gemm_fused<1><<<dim3(T_ / 128, 6), blk, 0, stream>>>(
        ch, cl, Wo, Wo, Wo, bo, bo, bo, 1.0f, out,
        nullptr, nullptr, nullptr, nullptr, nullptr, nullptr);
}

// Round 7
// 850.962 us; speedup vs baseline: 1.4020x; 1.1602x over previous
//
#include <hip/hip_runtime.h>
#include <math.h>

// Problem constants
#define R_  128
#define C_  256
#define E_  768
#define H_  12
#define DK_ 64
#define T_  (R_*C_)       // 32768 tokens
#define RS_ 8             // split-K over rows in attn kernel
#define LP  40            // LDS pitch for ctx V tile (padded transpose layout)

typedef __attribute__((ext_vector_type(8))) short          bf16x8;
typedef __attribute__((ext_vector_type(4))) float          f32x4;
typedef __attribute__((ext_vector_type(4))) unsigned short u16x4;
typedef __attribute__((ext_vector_type(8))) unsigned short u16x8;

struct HL { unsigned short h, l; };

// fp32 -> (hi, lo) bf16 split via truncation. hi+lo represents f with ~2^-16
// relative error; lo = f - hi is exact in fp32 (Sterbenz), then truncated.
__device__ __forceinline__ HL split2(float f) {
    HL o;
    unsigned int u = __float_as_uint(f);
    o.h = (unsigned short)(u >> 16);
    float r = f - __uint_as_float(u & 0xFFFF0000u);
    o.l = (unsigned short)(__float_as_uint(r) >> 16);
    return o;
}

// async global->LDS, 16 B per lane. LDS dest is wave-uniform base + lane*16.
__device__ __forceinline__ void gload16(const void* g, void* l) {
    __builtin_amdgcn_global_load_lds(
        (const __attribute__((address_space(1))) unsigned int*)g,
        (__attribute__((address_space(3))) unsigned int*)l,
        16, 0, 0);
}

// ---------------------------------------------------------------------------
// Pre-split: fp32 -> planar (hi, lo) bf16. 8 elems/thread, exact grids only.
// ---------------------------------------------------------------------------
__global__ __launch_bounds__(256) void split_kernel(
    const float* __restrict__ src,
    unsigned short* __restrict__ h, unsigned short* __restrict__ l)
{
    const size_t i = ((size_t)blockIdx.x * 256 + threadIdx.x) * 8;
    float4 f0 = *(const float4*)(src + i);
    float4 f1 = *(const float4*)(src + i + 4);
    float v[8] = { f0.x, f0.y, f0.z, f0.w, f1.x, f1.y, f1.z, f1.w };
    u16x8 hh, ll;
    #pragma unroll
    for (int j = 0; j < 8; ++j) { HL e = split2(v[j]); hh[j] = e.h; ll[j] = e.l; }
    *(u16x8*)(h + i) = hh;
    *(u16x8*)(l + i) = ll;
}

// ---------------------------------------------------------------------------
// GEMM: Y[m,n] = (sum_k A[m,k]*B[n,k] + bias[n]) * scale
// R2-proven structure (best measured: 138 us/GEMM): all operands pre-split
// planar bf16, 128x128 block tile, BK=32, 4 waves (2x2 of 64x64), dbuf LDS,
// ONE __syncthreads per K-step, mfma_f32_16x16x32_bf16, 3-term hi/lo.
// Staging: wave w stages tile w via 8x gload16; granule swizzle g^((r>>1)&3)
// via pre-swizzled global source (LDS dest linear); reads XOR the same term
// -> conflict-free ds_read_b128.
//
// T1 XCD-aware block swizzle. 1D grid 1536 (%8==0 -> bijective):
// swz=(bid%8)*192+bid/8; decode n-FASTEST (n=swz%6) so the 6 n-blocks that
// share an A-tile run consecutively on the SAME XCD -> A-tile served from
// that XCD's L2 instead of re-fetched from HBM (R2 FETCH=221MB vs ~105 ideal).
// OMODE 0: write split output (Yh, Yl).  OMODE 1: write fp32 Y.
// ---------------------------------------------------------------------------
template<int OMODE>
__global__ __launch_bounds__(256, 2) void gemm_kernel(
    const unsigned short* __restrict__ Ah, const unsigned short* __restrict__ Al,
    const unsigned short* __restrict__ Bh, const unsigned short* __restrict__ Bl,
    const float* __restrict__ bias, float scale,
    float* __restrict__ Y32, unsigned short* __restrict__ Yh, unsigned short* __restrict__ Yl)
{
    __shared__ __align__(16) unsigned short smem[2][16384];   // 64 KB

    const int bid = blockIdx.x;                    // 1536 blocks
    const int swz = (bid & 7) * 192 + (bid >> 3);  // XCD-chunked, bijective
    const int m0  = (swz / 6) * 128;
    const int n0  = (swz % 6) * 128;

    const int tid  = threadIdx.x;
    const int wave = tid >> 6, lane = tid & 63;
    const int wm   = (wave & 1) * 64, wn = (wave >> 1) * 64;
    const int fr   = lane & 15;
    const int kqs  = (((lane >> 4) ^ ((fr >> 1) & 3)) * 8);  // swizzled read offset

    // staging: lane -> (row = l>>2, slot = l&3); source granule = slot ^ ((l>>3)&3)
    const int lrow = lane >> 2;
    const int gd   = (lane & 3) ^ ((lane >> 3) & 3);
    const unsigned short* gsrc = (wave == 0) ? Ah : (wave == 1) ? Al
                               : (wave == 2) ? Bh : Bl;
    const int rbase = (wave < 2) ? m0 : n0;
    const unsigned short* sp = gsrc + (size_t)(rbase + lrow) * E_ + 8 * gd;
    const int ltoff = wave * 4096;

    f32x4 acc[4][4] = {};

    // prologue: stage K-tile 0 into buffer 0
    {
        unsigned short* lt = &smem[0][ltoff];
        #pragma unroll
        for (int i = 0; i < 8; ++i)
            gload16(sp + (size_t)i * 16 * E_, lt + i * 512);
    }

    int cur = 0;
    for (int k0 = 0; k0 < E_; k0 += 32) {
        __syncthreads();   // buf[cur] staged & visible; prev reads retired
        if (k0 + 32 < E_) {
            unsigned short* lt = &smem[cur ^ 1][ltoff];
            #pragma unroll
            for (int i = 0; i < 8; ++i)
                gload16(sp + k0 + 32 + (size_t)i * 16 * E_, lt + i * 512);
        }
        const unsigned short* AsH = smem[cur];
        const unsigned short* AsL = smem[cur] + 4096;
        const unsigned short* BsH = smem[cur] + 8192;
        const unsigned short* BsL = smem[cur] + 12288;

        bf16x8 a_h[4], a_l[4], b_h[4], b_l[4];
        #pragma unroll
        for (int t = 0; t < 4; ++t) {
            a_h[t] = *(const bf16x8*)&AsH[(wm + t * 16 + fr) * 32 + kqs];
            a_l[t] = *(const bf16x8*)&AsL[(wm + t * 16 + fr) * 32 + kqs];
            b_h[t] = *(const bf16x8*)&BsH[(wn + t * 16 + fr) * 32 + kqs];
            b_l[t] = *(const bf16x8*)&BsL[(wn + t * 16 + fr) * 32 + kqs];
        }
        #pragma unroll
        for (int i = 0; i < 4; ++i)
            #pragma unroll
            for (int j = 0; j < 4; ++j) {
                acc[i][j] = __builtin_amdgcn_mfma_f32_16x16x32_bf16(a_h[i], b_h[j], acc[i][j], 0, 0, 0);
                acc[i][j] = __builtin_amdgcn_mfma_f32_16x16x32_bf16(a_h[i], b_l[j], acc[i][j], 0, 0, 0);
                acc[i][j] = __builtin_amdgcn_mfma_f32_16x16x32_bf16(a_l[i], b_h[j], acc[i][j], 0, 0, 0);
            }
        cur ^= 1;
    }

    // ---- epilogue: per-wave LDS repack -> wide coalesced stores ----
    float* rep = (float*)&smem[0][0] + wave * 1024;   // [16][64] per wave
    const int mr = lane >> 2;
    const int nc = (lane & 3) * 16;
    #pragma unroll
    for (int ti = 0; ti < 4; ++ti) {
        __syncthreads();
        #pragma unroll
        for (int tj = 0; tj < 4; ++tj)
            #pragma unroll
            for (int r = 0; r < 4; ++r)
                rep[((lane >> 4) * 4 + r) * 64 + tj * 16 + fr] = acc[ti][tj][r];
        __syncthreads();
        float v[16];
        #pragma unroll
        for (int c = 0; c < 4; ++c)
            *(float4*)&v[4 * c] = *(const float4*)&rep[mr * 64 + nc + 4 * c];
        const int gm = m0 + wm + ti * 16 + mr;
        const int gn = n0 + wn + nc;
        if constexpr (OMODE == 1) {
            #pragma unroll
            for (int c = 0; c < 4; ++c) {
                float4 bv = *(const float4*)&bias[gn + 4 * c];
                float4 o;
                o.x = (v[4*c+0] + bv.x) * scale; o.y = (v[4*c+1] + bv.y) * scale;
                o.z = (v[4*c+2] + bv.z) * scale; o.w = (v[4*c+3] + bv.w) * scale;
                *(float4*)&Y32[(size_t)gm * E_ + gn + 4 * c] = o;
            }
        } else {
            unsigned short hh[16], ll[16];
            #pragma unroll
            for (int c = 0; c < 4; ++c) {
                float4 bv = *(const float4*)&bias[gn + 4 * c];
                HL e0 = split2((v[4*c+0] + bv.x) * scale);
                HL e1 = split2((v[4*c+1] + bv.y) * scale);
                HL e2 = split2((v[4*c+2] + bv.z) * scale);
                HL e3 = split2((v[4*c+3] + bv.w) * scale);
                hh[4*c+0] = e0.h; ll[4*c+0] = e0.l;
                hh[4*c+1] = e1.h; ll[4*c+1] = e1.l;
                hh[4*c+2] = e2.h; ll[4*c+2] = e2.l;
                hh[4*c+3] = e3.h; ll[4*c+3] = e3.l;
            }
            u16x8 H0, H1, L0, L1;
            #pragma unroll
            for (int j = 0; j < 8; ++j) { H0[j] = hh[j]; H1[j] = hh[8+j]; L0[j] = ll[j]; L1[j] = ll[8+j]; }
            *(u16x8*)&Yh[(size_t)gm * E_ + gn]     = H0;
            *(u16x8*)&Yh[(size_t)gm * E_ + gn + 8] = H1;
            *(u16x8*)&Yl[(size_t)gm * E_ + gn]     = L0;
            *(u16x8*)&Yl[(size_t)gm * E_ + gn + 8] = L1;
        }
    }
}

// ---------------------------------------------------------------------------
// Pooled attention logits, split-K over rows: part[rc,h,i,j] =
//   sum_{r in chunk rc} sum_d q[r,i,h,d] * k[r,j,h,d]
// 128x128 (i,j) tile per block, K-chunk = 16 rows * 64 d = 1024 (32 steps).
// R2-exact structure + T1 swizzle: 1D grid 384 (%8==0); chunk of 48 keeps the
// 4 (i,j)-blocks of each z-slice on one XCD (shared Q/K rows -> L2 hits).
// ---------------------------------------------------------------------------
__global__ __launch_bounds__(256, 2) void attn_mfma(
    const unsigned short* __restrict__ Qh, const unsigned short* __restrict__ Ql,
    const unsigned short* __restrict__ Kh, const unsigned short* __restrict__ Kl,
    float* __restrict__ part)
{
    __shared__ __align__(16) unsigned short smem[2][16384];

    const int bid = blockIdx.x;                   // 384 blocks
    const int swz = (bid & 7) * 48 + (bid >> 3);
    const int hz  = swz >> 2;                     // h * RS_ + rc
    const int ij  = swz & 3;
    const int i0  = (ij & 1) * 128;
    const int j0  = (ij >> 1) * 128;
    const int h   = hz >> 3;
    const int rc  = hz & 7;

    const int tid  = threadIdx.x;
    const int wave = tid >> 6, lane = tid & 63;
    const int wm   = (wave & 1) * 64, wn = (wave >> 1) * 64;
    const int fr   = lane & 15;
    const int kqs  = (((lane >> 4) ^ ((fr >> 1) & 3)) * 8);

    const int lrow = lane >> 2;
    const int gd   = (lane & 3) ^ ((lane >> 3) & 3);
    const unsigned short* gsrc = (wave == 0) ? Qh : (wave == 1) ? Ql
                               : (wave == 2) ? Kh : Kl;
    const int rbase = (wave < 2) ? i0 : j0;
    const int ltoff = wave * 4096;
    const unsigned short* sp0 =
        gsrc + ((size_t)(rc * 16 * C_) + rbase + lrow) * E_ + h * DK_ + 8 * gd;

    f32x4 acc[4][4] = {};

    // prologue: stage step 0 into buffer 0
    {
        unsigned short* lt = &smem[0][ltoff];
        #pragma unroll
        for (int i = 0; i < 8; ++i)
            gload16(sp0 + (size_t)i * 16 * E_, lt + i * 512);
    }

    int cur = 0;
    for (int s = 0; s < 32; ++s) {
        __syncthreads();
        if (s + 1 < 32) {
            const int sn = s + 1;
            const unsigned short* sp =
                sp0 + (size_t)(sn >> 1) * C_ * E_ + (sn & 1) * 32;
            unsigned short* lt = &smem[cur ^ 1][ltoff];
            #pragma unroll
            for (int i = 0; i < 8; ++i)
                gload16(sp + (size_t)i * 16 * E_, lt + i * 512);
        }
        const unsigned short* AsH = smem[cur];
        const unsigned short* AsL = smem[cur] + 4096;
        const unsigned short* BsH = smem[cur] + 8192;
        const unsigned short* BsL = smem[cur] + 12288;

        bf16x8 a_h[4], a_l[4], b_h[4], b_l[4];
        #pragma unroll
        for (int t = 0; t < 4; ++t) {
            a_h[t] = *(const bf16x8*)&AsH[(wm + t * 16 + fr) * 32 + kqs];
            a_l[t] = *(const bf16x8*)&AsL[(wm + t * 16 + fr) * 32 + kqs];
            b_h[t] = *(const bf16x8*)&BsH[(wn + t * 16 + fr) * 32 + kqs];
            b_l[t] = *(const bf16x8*)&BsL[(wn + t * 16 + fr) * 32 + kqs];
        }
        #pragma unroll
        for (int i = 0; i < 4; ++i)
            #pragma unroll
            for (int j = 0; j < 4; ++j) {
                acc[i][j] = __builtin_amdgcn_mfma_f32_16x16x32_bf16(a_h[i], b_h[j], acc[i][j], 0, 0, 0);
                acc[i][j] = __builtin_amdgcn_mfma_f32_16x16x32_bf16(a_h[i], b_l[j], acc[i][j], 0, 0, 0);
                acc[i][j] = __builtin_amdgcn_mfma_f32_16x16x32_bf16(a_l[i], b_h[j], acc[i][j], 0, 0, 0);
            }
        cur ^= 1;
    }

    float* rep = (float*)&smem[0][0] + wave * 1024;
    const int mr = lane >> 2;
    const int nc = (lane & 3) * 16;
    #pragma unroll
    for (int ti = 0; ti < 4; ++ti) {
        __syncthreads();
        #pragma unroll
        for (int tj = 0; tj < 4; ++tj)
            #pragma unroll
            for (int r = 0; r < 4; ++r)
                rep[((lane >> 4) * 4 + r) * 64 + tj * 16 + fr] = acc[ti][tj][r];
        __syncthreads();
        const int gi = i0 + wm + ti * 16 + mr;
        const int gj = j0 + wn + nc;
        #pragma unroll
        for (int c = 0; c < 4; ++c) {
            float4 o = *(const float4*)&rep[mr * 64 + nc + 4 * c];
            *(float4*)&part[((size_t)(rc * H_ + h) * C_ + gi) * C_ + gj + 4 * c] = o;
        }
    }
}

// ---------------------------------------------------------------------------
// Reduce RS_ partials + row softmax + write fp32 probs and bf16 split.
// One 256-thread block per (h, i) row.
// ---------------------------------------------------------------------------
__global__ __launch_bounds__(256) void softmax_split(
    const float* __restrict__ part, float* __restrict__ probs,
    unsigned short* __restrict__ ph, unsigned short* __restrict__ pl)
{
    const int row = blockIdx.x;            // h * C_ + i
    const int j = threadIdx.x;
    const int wave = j >> 6, lane = j & 63;

    float s = 0.0f;
    #pragma unroll
    for (int rcn = 0; rcn < RS_; ++rcn)
        s += part[((size_t)rcn * H_ * C_ + row) * C_ + j];

    float m = s;
    #pragma unroll
    for (int off = 32; off > 0; off >>= 1)
        m = fmaxf(m, __shfl_down(m, off, 64));
    __shared__ float redm[4];
    if (lane == 0) redm[wave] = m;
    __syncthreads();
    m = fmaxf(fmaxf(redm[0], redm[1]), fmaxf(redm[2], redm[3]));

    float e = expf(s - m);
    float t = e;
    #pragma unroll
    for (int off = 32; off > 0; off >>= 1)
        t += __shfl_down(t, off, 64);
    __shared__ float reds[4];
    if (lane == 0) reds[wave] = t;
    __syncthreads();
    t = reds[0] + reds[1] + reds[2] + reds[3];

    float p = e / t;
    probs[(size_t)row * C_ + j] = p;
    HL sp = split2(p);
    ph[(size_t)row * C_ + j] = sp.h;
    pl[(size_t)row * C_ + j] = sp.l;
}

// ---------------------------------------------------------------------------
// Context: C[r*C+i, h*64+d] = sum_j P[h,i,j] * V[r*C+j, h*64+d], split output.
// Per (i-block, r, h): M=128(i), N=64(d), K=256(j), BK=32 -> 8 steps.
//
// R2-style dbuf pipeline (prefetch t+1 overlaps compute of t; the single
// __syncthreads per step is the fence) + P staged via gload16 with the gemm
// granule swizzle (conflict-free b128 reads) + V prefetch T14-style
// (global->reg issue BEFORE frag reads/MFMA, transpose ds_write after).
// T1 swizzle: 1D grid 3072 (%8==0); chunk 384 keeps same-(h,i0) blocks
// (which share a P-tile) and i0-pairs (which share V) on one XCD.
// ---------------------------------------------------------------------------
__global__ __launch_bounds__(256, 2) void ctx_mfma(
    const unsigned short* __restrict__ Ph, const unsigned short* __restrict__ Pl,
    const unsigned short* __restrict__ Vh, const unsigned short* __restrict__ Vl,
    unsigned short* __restrict__ Ch, unsigned short* __restrict__ Cl)
{
    // per buf: PsH[128][32] | PsL[128][32] | VsH[64][LP] | VsL[64][LP]
    __shared__ __align__(16) unsigned short smem[2][13312];   // 52 KB

    const int bid = blockIdx.x;                    // 3072 blocks
    const int swz = (bid & 7) * 384 + (bid >> 3);
    const int h   = swz >> 8;                      // 0..11
    const int rem = swz & 255;
    const int r   = rem >> 1;                      // 0..127
    const int i0  = (rem & 1) * 128;

    const int tid  = threadIdx.x;
    const int wave = tid >> 6, lane = tid & 63;
    const int wm   = (wave & 1) * 64, wn = (wave >> 1) * 32;
    const int fr   = lane & 15;
    const int kq   = (lane >> 4) * 8;
    const int kqs  = (((lane >> 4) ^ ((fr >> 1) & 3)) * 8);   // swizzled P read

    // P staging via gload16: wave w -> plane w>>1, rows (w&1)*64 .. +63
    const int lrow   = lane >> 2;
    const int gd     = (lane & 3) ^ ((lane >> 3) & 3);
    const int pplane = wave >> 1;
    const int prhalf = (wave & 1) * 64;
    const unsigned short* psrc = (pplane ? Pl : Ph)
        + ((size_t)(h * C_) + i0 + prhalf + lrow) * C_ + 8 * gd;
    const int ptoff = pplane * 4096 + prhalf * 32;

    // V transpose staging (regs -> LDS [64 d][LP])
    const int vjj = tid & 31;
    const int vdg = tid >> 5;             // 0..7
    const unsigned short* vhsrc = Vh + ((size_t)(r * C_) + vjj) * E_ + h * DK_ + vdg * 8;
    const unsigned short* vlsrc = Vl + ((size_t)(r * C_) + vjj) * E_ + h * DK_ + vdg * 8;

    f32x4 acc[4][2] = {};

    // prologue: stage step 0 into buffer 0
    {
        #pragma unroll
        for (int i = 0; i < 4; ++i)
            gload16(psrc + (size_t)i * 16 * C_, &smem[0][ptoff + i * 512]);
        u16x8 v_h = *(const u16x8*)vhsrc;
        u16x8 v_l = *(const u16x8*)vlsrc;
        #pragma unroll
        for (int u = 0; u < 8; ++u) {
            smem[0][8192  + (vdg * 8 + u) * LP + vjj] = v_h[u];
            smem[0][10752 + (vdg * 8 + u) * LP + vjj] = v_l[u];
        }
    }

    for (int s = 0; s < 8; ++s) {
        const int cur = s & 1;
        __syncthreads();   // buf[cur] staged & visible; prev reads of buf^1 done

        // prefetch t+1: issue V reg-loads FIRST (latency), then P gloads;
        // transpose-write of V lands after the MFMAs (T14 split).
        u16x8 v_h, v_l;
        const bool pf = (s + 1 < 8);
        if (pf) {
            const int jb = (s + 1) * 32;
            v_h = *(const u16x8*)(vhsrc + (size_t)jb * E_);
            v_l = *(const u16x8*)(vlsrc + (size_t)jb * E_);
            #pragma unroll
            for (int i = 0; i < 4; ++i)
                gload16(psrc + jb + (size_t)i * 16 * C_,
                        &smem[cur ^ 1][ptoff + i * 512]);
        }

        const unsigned short* PsH = smem[cur];
        const unsigned short* PsL = smem[cur] + 4096;
        const unsigned short* VsH = smem[cur] + 8192;
        const unsigned short* VsL = smem[cur] + 10752;

        bf16x8 p_h[4], p_l[4], w_h[2], w_l[2];
        #pragma unroll
        for (int t = 0; t < 4; ++t) {
            p_h[t] = *(const bf16x8*)&PsH[(wm + t * 16 + fr) * 32 + kqs];
            p_l[t] = *(const bf16x8*)&PsL[(wm + t * 16 + fr) * 32 + kqs];
        }
        #pragma unroll
        for (int t = 0; t < 2; ++t) {
            w_h[t] = *(const bf16x8*)&VsH[(wn + t * 16 + fr) * LP + kq];
            w_l[t] = *(const bf16x8*)&VsL[(wn + t * 16 + fr) * LP + kq];
        }
        #pragma unroll
        for (int i = 0; i < 4; ++i)
            #pragma unroll
            for (int j = 0; j < 2; ++j) {
                acc[i][j] = __builtin_amdgcn_mfma_f32_16x16x32_bf16(p_h[i], w_h[j], acc[i][j], 0, 0, 0);
                acc[i][j] = __builtin_amdgcn_mfma_f32_16x16x32_bf16(p_h[i], w_l[j], acc[i][j], 0, 0, 0);
                acc[i][j] = __builtin_amdgcn_mfma_f32_16x16x32_bf16(p_l[i], w_h[j], acc[i][j], 0, 0, 0);
            }

        if (pf) {
            #pragma unroll
            for (int u = 0; u < 8; ++u) {
                smem[cur ^ 1][8192  + (vdg * 8 + u) * LP + vjj] = v_h[u];
                smem[cur ^ 1][10752 + (vdg * 8 + u) * LP + vjj] = v_l[u];
            }
        }
    }

    float* rep = (float*)&smem[0][0] + wave * 512;   // [16][32] per wave
    const int mr = lane >> 2;
    const int nc = (lane & 3) * 8;
    #pragma unroll
    for (int ti = 0; ti < 4; ++ti) {
        __syncthreads();
        #pragma unroll
        for (int tj = 0; tj < 2; ++tj)
            #pragma unroll
            for (int rr = 0; rr < 4; ++rr)
                rep[((lane >> 4) * 4 + rr) * 32 + tj * 16 + fr] = acc[ti][tj][rr];
        __syncthreads();
        float v[8];
        *(float4*)&v[0] = *(const float4*)&rep[mr * 32 + nc];
        *(float4*)&v[4] = *(const float4*)&rep[mr * 32 + nc + 4];
        const int gm = r * C_ + i0 + wm + ti * 16 + mr;
        const int gn = h * DK_ + wn + nc;
        u16x8 H8, L8;
        #pragma unroll
        for (int jj = 0; jj < 8; ++jj) { HL e = split2(v[jj]); H8[jj] = e.h; L8[jj] = e.l; }
        *(u16x8*)&Ch[(size_t)gm * E_ + gn] = H8;
        *(u16x8*)&Cl[(size_t)gm * E_ + gn] = L8;
    }
}

// ---------------------------------------------------------------------------
extern "C" void kernel_launch(void* const* d_in, const int* in_sizes, int n_in,
                              void* d_out, int out_size, void* d_ws, size_t ws_size,
                              hipStream_t stream)
{
    (void)in_sizes; (void)n_in; (void)out_size; (void)ws_size;

    const float* x  = (const float*)d_in[0];
    const float* Wq = (const float*)d_in[1];
    const float* bq = (const float*)d_in[2];
    const float* Wk = (const float*)d_in[3];
    const float* bk = (const float*)d_in[4];
    const float* Wv = (const float*)d_in[5];
    const float* bv = (const float*)d_in[6];
    const float* Wo = (const float*)d_in[7];
    const float* bo = (const float*)d_in[8];

    float* out   = (float*)d_out;
    float* probs = out + (size_t)T_ * E_;
    float* part  = out;                     // scratch: out region free until attn

    // ws: 6 planar bf16 buffers of T_*E_ ushorts = 302 MB (unchanged).
    const size_t QN = (size_t)T_ * E_;
    const size_t WN = (size_t)E_ * E_;
    unsigned short* qh = (unsigned short*)d_ws;
    unsigned short* ql = qh + QN;
    unsigned short* kh = ql + QN;
    unsigned short* kl = kh + QN;
    unsigned short* vh = kl + QN;
    unsigned short* vl = vh + QN;
    unsigned short* ph = kh;                 // reuse kh plane (dead after attn)
    unsigned short* pl = kh + (size_t)H_ * C_ * C_;
    unsigned short* ch = qh;                 // reuse q planes (dead after attn)
    unsigned short* cl = ql;

    // Scratch overlays (no new workspace):
    //   xh/xl   -> out region: dead before attn writes `part`.
    //   wsph/l  -> probs tail region (3.1 MB): dead before softmax writes probs.
    //   woh/wol -> kl plane: dead after attn, survives softmax/ctx/gemm4.
    unsigned short* xh   = (unsigned short*)out;
    unsigned short* xl   = xh + QN;
    unsigned short* wsph = (unsigned short*)probs;
    unsigned short* wspl = wsph + WN;
    unsigned short* woh  = kl;
    unsigned short* wol  = kl + WN;

    const float scaling = 0.125f / sqrtf(128.0f);   // DK^-0.5 / sqrt(R)

    dim3 blk(256);
    const int xblocks = (int)(QN / 2048);   // 8 elems/thread, exact
    const int wblocks = (int)(WN / 2048);

    split_kernel<<<dim3(xblocks), blk, 0, stream>>>(x, xh, xl);

    split_kernel<<<dim3(wblocks), blk, 0, stream>>>(Wq, wsph, wspl);
    gemm_kernel<0><<<dim3(1536), blk, 0, stream>>>(
        xh, xl, wsph, wspl, bq, scaling, nullptr, qh, ql);

    split_kernel<<<dim3(wblocks), blk, 0, stream>>>(Wk, wsph, wspl);
    gemm_kernel<0><<<dim3(1536), blk, 0, stream>>>(
        xh, xl, wsph, wspl, bk, 1.0f, nullptr, kh, kl);

    split_kernel<<<dim3(wblocks), blk, 0, stream>>>(Wv, wsph, wspl);
    gemm_kernel<0><<<dim3(1536), blk, 0, stream>>>(
        xh, xl, wsph, wspl, bv, 1.0f, nullptr, vh, vl);

    attn_mfma<<<dim3(384), blk, 0, stream>>>(qh, ql, kh, kl, part);

    split_kernel<<<dim3(wblocks), blk, 0, stream>>>(Wo, woh, wol);   // kl plane now dead

    softmax_split<<<dim3(H_ * C_), blk, 0, stream>>>(part, probs, ph, pl);
    ctx_mfma<<<dim3(3072), blk, 0, stream>>>(ph, pl, vh, vl, ch, cl);

    gemm_kernel<1><<<dim3(1536), blk, 0, stream>>>(
        ch, cl, woh, wol, bo, 1.0f, out, nullptr, nullptr);
}